// Round 1
// baseline (208.749 us; speedup 1.0000x reference)
//
#include <hip/hip_runtime.h>
#include <hip/hip_bf16.h>
#include <stdint.h>

#define TT   2048
#define EMB  1024
#define SDIM 64
#define LOG2E 1.4426950408889634f

typedef float f32x4 __attribute__((ext_vector_type(4)));
typedef short short8 __attribute__((ext_vector_type(8)));

__device__ __forceinline__ ushort f2bf(float f) {
    uint32_t u = __builtin_bit_cast(uint32_t, f);
    u += 0x7FFFu + ((u >> 16) & 1u);
    return (ushort)(u >> 16);
}

__device__ __forceinline__ short8 cvt8(const float* p) {
    f32x4 a = *(const f32x4*)p;
    f32x4 b = *(const f32x4*)(p + 4);
    short8 r;
    r[0] = (short)f2bf(a[0]); r[1] = (short)f2bf(a[1]);
    r[2] = (short)f2bf(a[2]); r[3] = (short)f2bf(a[3]);
    r[4] = (short)f2bf(b[0]); r[5] = (short)f2bf(b[1]);
    r[6] = (short)f2bf(b[2]); r[7] = (short)f2bf(b[3]);
    return r;
}

// ---------------- kernel 0: weight convert f32 -> bf16 ----------------
// Wq gets scale^2 = 2^-5 (exact) and log2(e) folded in, so attention logits
// are directly in exp2 domain.
__global__ __launch_bounds__(256) void cvt_w(const float* __restrict__ Wk, const float* __restrict__ Wq,
                                             const float* __restrict__ Wv, const float* __restrict__ Wu,
                                             ushort* __restrict__ Wk16, ushort* __restrict__ Wq16,
                                             ushort* __restrict__ Wv16, ushort* __restrict__ Wu16) {
    int i = blockIdx.x * 256 + threadIdx.x;   // grid covers 1M = Wu elements
    Wu16[i] = f2bf(Wu[i]);
    if (i < 4096) {
        Wk16[i] = f2bf(Wk[i]);
        Wq16[i] = f2bf(Wq[i] * (0.03125f * LOG2E));
        Wv16[i] = f2bf(Wv[i]);
    }
}

// ---------------- kernel 1: QKV projection (MFMA) ----------------
// rows ordered (b,h,t); Q/K/V stored bf16 layout (B,H,T,S)
__global__ __launch_bounds__(256) void qkv(const float* __restrict__ x,
                                           const ushort* __restrict__ Wk16, const ushort* __restrict__ Wq16,
                                           const ushort* __restrict__ Wv16,
                                           ushort* __restrict__ Qw, ushort* __restrict__ Kw, ushort* __restrict__ Vw) {
    const int tid = threadIdx.x;
    const int wave = tid >> 6, lane = tid & 63;
    const int c = lane & 15, g = lane >> 4;
    const int rblk = (blockIdx.x * 4 + wave) * 16;     // token-head row base (b,h,t flat)
    const int bh = rblk >> 11;                          // b*16 + h
    const int tbase = rblk & (TT - 1);
    const int b = bh >> 4, h = bh & 15;

    const float* xrow = x + ((size_t)(b * TT + tbase + c) * EMB + h * SDIM);
    short8 a[2];
#pragma unroll
    for (int ks = 0; ks < 2; ++ks) a[ks] = cvt8(xrow + 32 * ks + 8 * g);

    f32x4 aq[4], ak[4], av[4];
#pragma unroll
    for (int n = 0; n < 4; ++n) { aq[n] = 0.f; ak[n] = 0.f; av[n] = 0.f; }

#pragma unroll
    for (int n = 0; n < 4; ++n) {
#pragma unroll
        for (int ks = 0; ks < 2; ++ks) {
            const size_t wo = (size_t)(16 * n + c) * SDIM + 32 * ks + 8 * g;
            short8 bq = *(const short8*)(Wq16 + wo);
            short8 bk = *(const short8*)(Wk16 + wo);
            short8 bv = *(const short8*)(Wv16 + wo);
            aq[n] = __builtin_amdgcn_mfma_f32_16x16x32_bf16(a[ks], bq, aq[n], 0, 0, 0);
            ak[n] = __builtin_amdgcn_mfma_f32_16x16x32_bf16(a[ks], bk, ak[n], 0, 0, 0);
            av[n] = __builtin_amdgcn_mfma_f32_16x16x32_bf16(a[ks], bv, av[n], 0, 0, 0);
        }
    }
    const size_t hb = (size_t)bh * TT * SDIM;
#pragma unroll
    for (int n = 0; n < 4; ++n)
#pragma unroll
        for (int i = 0; i < 4; ++i) {
            const size_t o = hb + (size_t)(tbase + 4 * g + i) * SDIM + 16 * n + c;
            Qw[o] = f2bf(aq[n][i]);
            Kw[o] = f2bf(ak[n][i]);
            Vw[o] = f2bf(av[n][i]);
        }
}

// ---------------- kernel 2: flash attention ----------------
// grid (qtile=16, bh=32), 512 threads = 8 waves x 16 q-rows (QBLK=128), KVBLK=64
__global__ __launch_bounds__(512) void attn(const ushort* __restrict__ Qw, const ushort* __restrict__ Kw,
                                            const ushort* __restrict__ Vw, ushort* __restrict__ AO) {
    __shared__ ushort Klds[64 * 64];       // [kv][s], XOR-swizzled 16B slots
    __shared__ ushort Vt[64 * 64];         // [s][kv], XOR-swizzled
    __shared__ ushort Plds[8][16 * 64];    // per-wave P tile [q][kv]

    const int tid = threadIdx.x;
    const int wave = tid >> 6, lane = tid & 63;
    const int c = lane & 15, g = lane >> 4;
    const int bh = blockIdx.y;
    const int qrow = blockIdx.x * 128 + wave * 16;
    const size_t base = (size_t)bh * TT * SDIM;

    short8 qa[2];
#pragma unroll
    for (int ks = 0; ks < 2; ++ks)
        qa[ks] = *(const short8*)(Qw + base + (size_t)(qrow + c) * SDIM + 32 * ks + 8 * g);

    f32x4 accO[4];
    float m_i[4], l_i[4];
#pragma unroll
    for (int n = 0; n < 4; ++n) accO[n] = 0.f;
#pragma unroll
    for (int i = 0; i < 4; ++i) { m_i[i] = -__builtin_inff(); l_i[i] = 0.f; }

    const int kK = tid >> 3, sK = (tid & 7) * 8;    // K staging: contiguous global reads
    const int kV = tid & 63, sV = (tid >> 6) * 8;   // V staging: conflict-free LDS writes

    for (int kt = 0; kt < 32; ++kt) {
        const int kvb = kt * 64;
        __syncthreads();
        {   // stage K tile (swizzled 16B blocks)
            uint4 kd = *(const uint4*)(Kw + base + (size_t)(kvb + kK) * SDIM + sK);
            *(uint4*)((char*)Klds + kK * 128 + ((sK * 2) ^ ((kK & 7) << 4))) = kd;
        }
        {   // stage V tile transposed: Vt[s][kv]
            uint4 vd = *(const uint4*)(Vw + base + (size_t)(kvb + kV) * SDIM + sV);
            const ushort* vp = (const ushort*)&vd;
#pragma unroll
            for (int j = 0; j < 8; ++j)
                *(ushort*)((char*)Vt + (sV + j) * 128 + ((kV * 2) ^ (j << 4))) = vp[j];
        }
        __syncthreads();

        // S = Q·K^T  (logits already in exp2 domain via Wq scaling)
        f32x4 S[4];
#pragma unroll
        for (int n = 0; n < 4; ++n) S[n] = 0.f;
#pragma unroll
        for (int n = 0; n < 4; ++n)
#pragma unroll
            for (int ks = 0; ks < 2; ++ks) {
                short8 bk = *(const short8*)((const char*)Klds + (16 * n + c) * 128 +
                                             ((64 * ks + 16 * g) ^ ((c & 7) << 4)));
                S[n] = __builtin_amdgcn_mfma_f32_16x16x32_bf16(qa[ks], bk, S[n], 0, 0, 0);
            }

        // online softmax: rows live on 16-lane groups
        float mt[4];
#pragma unroll
        for (int i = 0; i < 4; ++i)
            mt[i] = fmaxf(fmaxf(S[0][i], S[1][i]), fmaxf(S[2][i], S[3][i]));
#pragma unroll
        for (int i = 0; i < 4; ++i) {
            mt[i] = fmaxf(mt[i], __shfl_xor(mt[i], 1));
            mt[i] = fmaxf(mt[i], __shfl_xor(mt[i], 2));
            mt[i] = fmaxf(mt[i], __shfl_xor(mt[i], 4));
            mt[i] = fmaxf(mt[i], __shfl_xor(mt[i], 8));
        }
        float al[4], rs[4];
#pragma unroll
        for (int i = 0; i < 4; ++i) {
            float mn = fmaxf(m_i[i], mt[i]);
            al[i] = __builtin_amdgcn_exp2f(m_i[i] - mn);
            m_i[i] = mn; rs[i] = 0.f;
        }
#pragma unroll
        for (int n = 0; n < 4; ++n)
#pragma unroll
            for (int i = 0; i < 4; ++i) {
                float p = __builtin_amdgcn_exp2f(S[n][i] - m_i[i]);
                S[n][i] = p; rs[i] += p;
            }
#pragma unroll
        for (int i = 0; i < 4; ++i) {
            rs[i] += __shfl_xor(rs[i], 1);
            rs[i] += __shfl_xor(rs[i], 2);
            rs[i] += __shfl_xor(rs[i], 4);
            rs[i] += __shfl_xor(rs[i], 8);
            l_i[i] = l_i[i] * al[i] + rs[i];
        }
#pragma unroll
        for (int n = 0; n < 4; ++n)
#pragma unroll
            for (int i = 0; i < 4; ++i) accO[n][i] *= al[i];

        // P -> per-wave LDS (D-layout write, A-layout read)
        char* myP = (char*)&Plds[wave][0];
#pragma unroll
        for (int n = 0; n < 4; ++n)
#pragma unroll
            for (int i = 0; i < 4; ++i) {
                int row = 4 * g + i;
                *(ushort*)(myP + row * 128 + (((16 * n + c) * 2) ^ ((row & 7) << 4))) = f2bf(S[n][i]);
            }
        __syncthreads();

        // O += P·V
#pragma unroll
        for (int ks = 0; ks < 2; ++ks) {
            short8 pa = *(const short8*)(myP + c * 128 + ((64 * ks + 16 * g) ^ ((c & 7) << 4)));
#pragma unroll
            for (int n = 0; n < 4; ++n) {
                short8 bv = *(const short8*)((const char*)Vt + (16 * n + c) * 128 +
                                             ((64 * ks + 16 * g) ^ ((c & 7) << 4)));
                accO[n] = __builtin_amdgcn_mfma_f32_16x16x32_bf16(pa, bv, accO[n], 0, 0, 0);
            }
        }
    }

    // epilogue: normalize, store AO bf16 (B,T,EMB)
    const int b = bh >> 4, h = bh & 15;
    float inv[4];
#pragma unroll
    for (int i = 0; i < 4; ++i) inv[i] = 1.f / l_i[i];
#pragma unroll
    for (int n = 0; n < 4; ++n)
#pragma unroll
        for (int i = 0; i < 4; ++i) {
            size_t o = (size_t)(b * TT + qrow + 4 * g + i) * EMB + h * SDIM + 16 * n + c;
            AO[o] = f2bf(accO[n][i] * inv[i]);
        }
}

// ---------------- kernel 3: output projection + bias ----------------
// grid (64, 16), 256 threads = 4 waves x 16 rows; tile 64x64, K=1024
__global__ __launch_bounds__(256) void oproj(const ushort* __restrict__ AO, const ushort* __restrict__ Wu16,
                                             const float* __restrict__ bu, float* __restrict__ out) {
    const int tid = threadIdx.x;
    const int wave = tid >> 6, lane = tid & 63;
    const int c = lane & 15, g = lane >> 4;
    const int rblk = blockIdx.x * 64 + wave * 16;
    const int ob = blockIdx.y * 64;

    f32x4 acc[4];
#pragma unroll
    for (int n = 0; n < 4; ++n) acc[n] = 0.f;

    for (int kt = 0; kt < 32; ++kt) {
        const int e0 = kt * 32;
        short8 a = *(const short8*)(AO + (size_t)(rblk + c) * EMB + e0 + 8 * g);
#pragma unroll
        for (int n = 0; n < 4; ++n) {
            short8 b = *(const short8*)(Wu16 + (size_t)(ob + 16 * n + c) * EMB + e0 + 8 * g);
            acc[n] = __builtin_amdgcn_mfma_f32_16x16x32_bf16(a, b, acc[n], 0, 0, 0);
        }
    }
#pragma unroll
    for (int n = 0; n < 4; ++n) {
        float bias = bu[ob + 16 * n + c];
#pragma unroll
        for (int i = 0; i < 4; ++i)
            out[(size_t)(rblk + 4 * g + i) * EMB + ob + 16 * n + c] = acc[n][i] + bias;
    }
}

extern "C" void kernel_launch(void* const* d_in, const int* in_sizes, int n_in,
                              void* d_out, int out_size, void* d_ws, size_t ws_size,
                              hipStream_t stream) {
    const float* x  = (const float*)d_in[0];
    const float* Wk = (const float*)d_in[1];
    const float* Wq = (const float*)d_in[2];
    const float* Wv = (const float*)d_in[3];
    const float* Wu = (const float*)d_in[4];
    const float* bu = (const float*)d_in[5];
    float* out = (float*)d_out;

    char* ws = (char*)d_ws;
    const size_t MB = 1024u * 1024u;
    ushort* Qw   = (ushort*)(ws);             // 8 MB  (B,H,T,S) bf16
    ushort* Kw   = (ushort*)(ws + 8 * MB);    // 8 MB
    ushort* Vw   = (ushort*)(ws + 16 * MB);   // 8 MB
    ushort* AO   = (ushort*)(ws + 24 * MB);   // 8 MB  (B,T,EMB) bf16
    ushort* Wu16 = (ushort*)(ws + 32 * MB);   // 2 MB
    ushort* Wk16 = (ushort*)(ws + 34 * MB);   // 8 KB x3
    ushort* Wq16 = Wk16 + 4096;
    ushort* Wv16 = Wk16 + 8192;

    cvt_w<<<dim3(4096), dim3(256), 0, stream>>>(Wk, Wq, Wv, Wu, Wk16, Wq16, Wv16, Wu16);
    qkv<<<dim3(1024), dim3(256), 0, stream>>>(x, Wk16, Wq16, Wv16, Qw, Kw, Vw);
    attn<<<dim3(16, 32), dim3(512), 0, stream>>>(Qw, Kw, Vw, AO);
    oproj<<<dim3(64, 16), dim3(256), 0, stream>>>(AO, Wu16, bu, out);
}